// Round 3
// baseline (712.841 us; speedup 1.0000x reference)
//
#include <hip/hip_runtime.h>

#define DEVI __device__ __forceinline__

namespace {

constexpr int Nn = 50000;   // nodes
constexpr int Ne = 800000;  // edges
constexpr int Fd = 128;     // feature dim
constexpr int Hd = 256;     // hidden
constexpr int Cd = 40;      // classes
constexpr int NB = (Nn + 255) / 256;  // 196 scan blocks

typedef __attribute__((ext_vector_type(8))) short s16x8;   // 8 bf16 (4 VGPR) MFMA frag
typedef __attribute__((ext_vector_type(4))) float f32x4;

DEVI unsigned short f2bf(float f) {
  unsigned int u = __builtin_bit_cast(unsigned int, f);
  u += 0x7fffu + ((u >> 16) & 1u);   // RNE
  return (unsigned short)(u >> 16);
}
DEVI float bf2f(unsigned short s) {
  return __builtin_bit_cast(float, ((unsigned int)s) << 16);
}

// ---------------- CSR build ----------------
__global__ void k_zero(int* cnt) {
  int i = blockIdx.x * 256 + threadIdx.x;
  if (i < Nn) cnt[i] = 0;
}

__global__ void k_count(const int* __restrict__ dst, int* __restrict__ cnt) {
  int e = blockIdx.x * 256 + threadIdx.x;
  if (e < Ne) atomicAdd(&cnt[dst[e]], 1);
}

// level 1: per-block sums of (cnt[i]+1)
__global__ __launch_bounds__(256) void k_partial(const int* __restrict__ cnt,
                                                 int* __restrict__ partial) {
  __shared__ int red[256];
  const int t = threadIdx.x;
  const int i = blockIdx.x * 256 + t;
  red[t] = (i < Nn) ? cnt[i] + 1 : 0;
  __syncthreads();
#pragma unroll
  for (int off = 128; off; off >>= 1) {
    if (t < off) red[t] += red[t + off];
    __syncthreads();
  }
  if (t == 0) partial[blockIdx.x] = red[0];
}

// level 2: scan the 196 partials (tiny, one block)
__global__ __launch_bounds__(256) void k_scan_small(const int* __restrict__ partial,
                                                    int* __restrict__ poffs,
                                                    int* __restrict__ rowptr) {
  __shared__ int s[256];
  const int t = threadIdx.x;
  const int v = (t < NB) ? partial[t] : 0;
  s[t] = v;
  __syncthreads();
#pragma unroll
  for (int off = 1; off < 256; off <<= 1) {
    int add = (t >= off) ? s[t - off] : 0;
    __syncthreads();
    s[t] += add;
    __syncthreads();
  }
  if (t < NB) poffs[t] = s[t] - v;        // exclusive
  if (t == NB - 1) rowptr[Nn] = s[t];     // total = Ne + Nn
}

// level 3: per-block scan + offset -> rowptr / cursor / dinv
__global__ __launch_bounds__(256) void k_rowptr(const int* __restrict__ cnt,
                                                const int* __restrict__ poffs,
                                                int* __restrict__ rowptr,
                                                int* __restrict__ cursor,
                                                float* __restrict__ dinv) {
  __shared__ int s[256];
  const int t = threadIdx.x;
  const int i = blockIdx.x * 256 + t;
  const int c = (i < Nn) ? cnt[i] + 1 : 0;
  s[t] = c;
  __syncthreads();
#pragma unroll
  for (int off = 1; off < 256; off <<= 1) {
    int add = (t >= off) ? s[t - off] : 0;
    __syncthreads();
    s[t] += add;
    __syncthreads();
  }
  if (i < Nn) {
    const int excl = s[t] - c + poffs[blockIdx.x];
    rowptr[i] = excl;
    cursor[i] = excl;
    dinv[i] = rsqrtf((float)c);
  }
}

__global__ void k_fill(const int* __restrict__ src, const int* __restrict__ dst,
                       const float* __restrict__ dinv, int* __restrict__ cursor,
                       int* __restrict__ csrs, float* __restrict__ csrn) {
  int e = blockIdx.x * 256 + threadIdx.x;
  if (e < Ne) {
    int s = src[e], d = dst[e];
    int pos = atomicAdd(&cursor[d], 1);
    csrs[pos] = s;
    csrn[pos] = dinv[s] * dinv[d];
  } else if (e < Ne + Nn) {
    int d = e - Ne;  // self loop
    int pos = atomicAdd(&cursor[d], 1);
    csrs[pos] = d;
    float v = dinv[d];
    csrn[pos] = v * v;
  }
}

// ---------------- weight transpose + bf16 cast: Wt[c][k] = W[k][c] ----------------
__global__ void k_wt(const float* __restrict__ W, unsigned short* __restrict__ Wt,
                     int K, int H, int Hpad) {
  int idx = blockIdx.x * 256 + threadIdx.x;
  if (idx >= Hpad * K) return;
  int c = idx / K, k = idx - c * K;
  float v = (c < H) ? W[(size_t)k * H + c] : 0.0f;
  Wt[idx] = f2bf(v);
}

// ---------------- GEMM: C[M x ncols] = A[M x K] @ W, bf16 MFMA ----------------
// Single col-pass: BN = NWC*64 (grid.y == 1), BM = (4/NWC)*64. 4 waves.
// MODE 0: A = bf16 row-major (lda elems)
// MODE 1: A(r,k) = feat[(k>>7)*Nn*Fd + r*Fd + (k&127)] * (ow ? ow[(k>>7)&1] : 1)  (f32 source)
template <int MODE, int NWC>
__global__ __launch_bounds__(256) void k_gemm(
    const void* __restrict__ Aptr, int lda, int K,
    const unsigned short* __restrict__ Wt,  // [BN][K] bf16 (padded)
    const float* __restrict__ ow, const float* __restrict__ bias,
    unsigned short* __restrict__ Cout, int ldc, int col_off, int ncols, int relu) {
  constexpr int WRN = 4 / NWC;
  constexpr int BM = WRN * 64;
  constexpr int BN = NWC * 64;
  constexpr int APT = BM / 32;  // vec8s per thread for A tile
  constexpr int BPT = BN / 32;  // vec8s per thread for B tile
  __shared__ short lA[BM * 64];
  __shared__ short lB[BN * 64];
  const int tid = threadIdx.x;
  const int lane = tid & 63;
  const int wid = tid >> 6;
  const int wr = wid / NWC;
  const int wc = wid % NWC;
  const int row0 = blockIdx.x * BM;

  f32x4 acc[4][4];
#pragma unroll
  for (int i = 0; i < 4; ++i)
#pragma unroll
    for (int j = 0; j < 4; ++j) acc[i][j] = (f32x4)0.0f;

  const s16x8 VZ = (s16x8)0;
  const int nkt = K >> 6;
  for (int kt = 0; kt < nkt; ++kt) {
    const int k0 = kt * 64;
    // ---- stage A tile (BM x 64 bf16), XOR-swizzled
#pragma unroll
    for (int i = 0; i < APT; ++i) {
      const int v = tid * APT + i;
      const int row = v >> 3;      // 0..BM-1
      const int c16 = v & 7;       // vec8 within row
      const int grow = row0 + row;
      const bool rv = grow < Nn;
      s16x8 val;
      if (MODE == 0) {
        const unsigned short* A = (const unsigned short*)Aptr;
        val = rv ? *(const s16x8*)(A + (size_t)grow * lda + k0 + c16 * 8) : VZ;
      } else {
        const float* feat = (const float*)Aptr;
        const int c = k0 >> 7;
        const float scale = ow ? ow[c & 1] : 1.0f;
        const float* p = feat + (size_t)c * ((size_t)Nn * Fd) + (size_t)grow * Fd +
                         (k0 & 127) + c16 * 8;
        f32x4 a = rv ? *(const f32x4*)p : (f32x4)0.0f;
        f32x4 b = rv ? *(const f32x4*)(p + 4) : (f32x4)0.0f;
#pragma unroll
        for (int q = 0; q < 4; ++q) val[q] = (short)f2bf(a[q] * scale);
#pragma unroll
        for (int q = 0; q < 4; ++q) val[4 + q] = (short)f2bf(b[q] * scale);
      }
      int byte = row * 128 + c16 * 16;
      byte ^= (row & 7) << 4;
      *(s16x8*)((char*)lA + byte) = val;
    }
    // ---- stage B tile (BN x 64 bf16) from pre-transposed Wt
#pragma unroll
    for (int i = 0; i < BPT; ++i) {
      const int v = tid * BPT + i;
      const int row = v >> 3;
      const int c16 = v & 7;
      s16x8 val = *(const s16x8*)(Wt + (size_t)row * K + k0 + c16 * 8);
      int byte = row * 128 + c16 * 16;
      byte ^= (row & 7) << 4;
      *(s16x8*)((char*)lB + byte) = val;
    }
    __syncthreads();
    // ---- compute: 2 k-slices of 32, 4x4 frags per wave
#pragma unroll
    for (int kk = 0; kk < 2; ++kk) {
      s16x8 af[4], bv[4];
#pragma unroll
      for (int mi = 0; mi < 4; ++mi) {
        int r = wr * 64 + mi * 16 + (lane & 15);
        int byte = r * 128 + kk * 64 + (lane >> 4) * 16;
        byte ^= (r & 7) << 4;
        af[mi] = *(const s16x8*)((const char*)lA + byte);
      }
#pragma unroll
      for (int ni = 0; ni < 4; ++ni) {
        int c = wc * 64 + ni * 16 + (lane & 15);
        int byte = c * 128 + kk * 64 + (lane >> 4) * 16;
        byte ^= (c & 7) << 4;
        bv[ni] = *(const s16x8*)((const char*)lB + byte);
      }
#pragma unroll
      for (int mi = 0; mi < 4; ++mi)
#pragma unroll
        for (int ni = 0; ni < 4; ++ni)
          acc[mi][ni] = __builtin_amdgcn_mfma_f32_16x16x32_bf16(af[mi], bv[ni], acc[mi][ni], 0, 0, 0);
    }
    __syncthreads();
  }

  // ---- epilogue: bias / relu / bf16 store
#pragma unroll
  for (int ni = 0; ni < 4; ++ni) {
    const int col = wc * 64 + ni * 16 + (lane & 15);
    if (col >= ncols) continue;
    const float bvl = bias ? bias[col] : 0.0f;
#pragma unroll
    for (int mi = 0; mi < 4; ++mi) {
      const int rb = row0 + wr * 64 + mi * 16 + ((lane >> 4) << 2);
#pragma unroll
      for (int q = 0; q < 4; ++q) {
        int r = rb + q;
        if (r < Nn) {
          float vv = acc[mi][ni][q] + bvl;
          if (relu) vv = fmaxf(vv, 0.0f);
          Cout[(size_t)r * ldc + col_off + col] = f2bf(vv);
        }
      }
    }
  }
}

// ---------------- gather (aggregate) 256-dim: one wave per node, sw-pipelined ----------------
__global__ __launch_bounds__(256) void k_gather(
    const unsigned short* __restrict__ m, const int* __restrict__ rowptr,
    const int* __restrict__ csrs, const float* __restrict__ csrn,
    const float* __restrict__ bias, unsigned short* __restrict__ outp,
    int ldc, int col_off) {
  const int wid = (blockIdx.x * 256 + threadIdx.x) >> 6;
  const int lane = threadIdx.x & 63;
  if (wid >= Nn) return;
  const int e0 = rowptr[wid], e1 = rowptr[wid + 1];
  float a0 = 0.f, a1 = 0.f, a2 = 0.f, a3 = 0.f;
  for (int base = e0; base < e1; base += 64) {
    const int idx = base + lane;
    int s_ = 0;
    float w_ = 0.f;
    if (idx < e1) { s_ = csrs[idx]; w_ = csrn[idx]; }
    const int cn = min(64, e1 - base);
    int s = __shfl(s_, 0);
    float w = __shfl(w_, 0);
    ushort4 v = *(const ushort4*)(m + (size_t)s * Hd + lane * 4);
    for (int j = 1; j < cn; ++j) {
      const int s2 = __shfl(s_, j);
      const float w2 = __shfl(w_, j);
      const ushort4 v2 = *(const ushort4*)(m + (size_t)s2 * Hd + lane * 4);
      a0 += w * bf2f(v.x);
      a1 += w * bf2f(v.y);
      a2 += w * bf2f(v.z);
      a3 += w * bf2f(v.w);
      w = w2; v = v2;
    }
    a0 += w * bf2f(v.x);
    a1 += w * bf2f(v.y);
    a2 += w * bf2f(v.z);
    a3 += w * bf2f(v.w);
  }
  a0 = fmaxf(a0 + bias[lane * 4 + 0], 0.f);
  a1 = fmaxf(a1 + bias[lane * 4 + 1], 0.f);
  a2 = fmaxf(a2 + bias[lane * 4 + 2], 0.f);
  a3 = fmaxf(a3 + bias[lane * 4 + 3], 0.f);
  ushort4 o;
  o.x = f2bf(a0); o.y = f2bf(a1); o.z = f2bf(a2); o.w = f2bf(a3);
  *(ushort4*)(outp + (size_t)wid * ldc + col_off + lane * 4) = o;
}

// ---------------- cls gather + bias + log_softmax (40 dims, lanes 0..9) ----------------
__global__ __launch_bounds__(256) void k_gcls(
    const unsigned short* __restrict__ mc, const int* __restrict__ rowptr,
    const int* __restrict__ csrs, const float* __restrict__ csrn,
    const float* __restrict__ clsb, float* __restrict__ outp) {
  const int wid = (blockIdx.x * 256 + threadIdx.x) >> 6;
  const int lane = threadIdx.x & 63;
  if (wid >= Nn) return;
  const bool act = lane < 10;
  const int e0 = rowptr[wid], e1 = rowptr[wid + 1];
  float a0 = 0.f, a1 = 0.f, a2 = 0.f, a3 = 0.f;
  for (int base = e0; base < e1; base += 64) {
    const int idx = base + lane;
    int s_ = 0;
    float w_ = 0.f;
    if (idx < e1) { s_ = csrs[idx]; w_ = csrn[idx]; }
    const int cn = min(64, e1 - base);
    int s = __shfl(s_, 0);
    float w = __shfl(w_, 0);
    ushort4 v = act ? *(const ushort4*)(mc + (size_t)s * Cd + lane * 4) : ushort4{0, 0, 0, 0};
    for (int j = 1; j < cn; ++j) {
      const int s2 = __shfl(s_, j);
      const float w2 = __shfl(w_, j);
      const ushort4 v2 = act ? *(const ushort4*)(mc + (size_t)s2 * Cd + lane * 4) : ushort4{0, 0, 0, 0};
      a0 += w * bf2f(v.x);
      a1 += w * bf2f(v.y);
      a2 += w * bf2f(v.z);
      a3 += w * bf2f(v.w);
      w = w2; v = v2;
    }
    a0 += w * bf2f(v.x);
    a1 += w * bf2f(v.y);
    a2 += w * bf2f(v.z);
    a3 += w * bf2f(v.w);
  }
  float l0 = 0.f, l1 = 0.f, l2 = 0.f, l3 = 0.f;
  if (act) {
    l0 = a0 + clsb[lane * 4 + 0];
    l1 = a1 + clsb[lane * 4 + 1];
    l2 = a2 + clsb[lane * 4 + 2];
    l3 = a3 + clsb[lane * 4 + 3];
  }
  float mx = act ? fmaxf(fmaxf(l0, l1), fmaxf(l2, l3)) : -3.4e38f;
#pragma unroll
  for (int off = 32; off; off >>= 1) mx = fmaxf(mx, __shfl_xor(mx, off));
  float se = act ? (expf(l0 - mx) + expf(l1 - mx) + expf(l2 - mx) + expf(l3 - mx)) : 0.f;
#pragma unroll
  for (int off = 32; off; off >>= 1) se += __shfl_xor(se, off);
  const float lse = mx + logf(se);
  if (act) {
    float* o1 = outp + (size_t)wid * Cd + lane * 4;
    float* o2 = outp + (size_t)Nn * Cd + (size_t)wid * Cd + lane * 4;
    o1[0] = l0 - lse; o1[1] = l1 - lse; o1[2] = l2 - lse; o1[3] = l3 - lse;
    o2[0] = l0; o2[1] = l1; o2[2] = l2; o2[3] = l3;
  }
}

}  // namespace

extern "C" void kernel_launch(void* const* d_in, const int* in_sizes, int n_in,
                              void* d_out, int out_size, void* d_ws, size_t ws_size,
                              hipStream_t stream) {
  (void)in_sizes; (void)n_in; (void)out_size; (void)ws_size;
  const float* x       = (const float*)d_in[0];
  const float* feature = (const float*)d_in[1];
  const int* src       = (const int*)d_in[2];
  const int* dst       = (const int*)d_in[3];
  const float* convW[3] = {(const float*)d_in[4], (const float*)d_in[6], (const float*)d_in[8]};
  const float* convB[3] = {(const float*)d_in[5], (const float*)d_in[7], (const float*)d_in[9]};
  const float* linW[3]  = {(const float*)d_in[10], (const float*)d_in[12], (const float*)d_in[14]};
  const float* linB[3]  = {(const float*)d_in[11], (const float*)d_in[13], (const float*)d_in[15]};
  const float* oweights = (const float*)d_in[16];
  const float* clsW     = (const float*)d_in[17];
  const float* clsB     = (const float*)d_in[18];
  float* out = (float*)d_out;

  char* wsp = (char*)d_ws;
  auto alloc = [&](size_t bytes) -> void* {
    void* p = wsp;
    wsp += (bytes + 255) & ~(size_t)255;
    return p;
  };
  int* cnt      = (int*)alloc((size_t)Nn * 4);
  int* cursor   = (int*)alloc((size_t)Nn * 4);
  int* rowptr   = (int*)alloc((size_t)(Nn + 1) * 4);
  float* dinv   = (float*)alloc((size_t)Nn * 4);
  int* partial  = (int*)alloc((size_t)NB * 4);
  int* poffs    = (int*)alloc((size_t)NB * 4);
  int* csrs     = (int*)alloc((size_t)(Ne + Nn) * 4);
  float* csrn   = (float*)alloc((size_t)(Ne + Nn) * 4);
  unsigned short* WtC0 = (unsigned short*)alloc((size_t)256 * 128 * 2);
  unsigned short* WtC1 = (unsigned short*)alloc((size_t)256 * 512 * 2);
  unsigned short* WtC2 = (unsigned short*)alloc((size_t)256 * 512 * 2);
  unsigned short* WtL0 = (unsigned short*)alloc((size_t)256 * 128 * 2);
  unsigned short* WtL1 = (unsigned short*)alloc((size_t)256 * 256 * 2);
  unsigned short* WtL2 = (unsigned short*)alloc((size_t)256 * 512 * 2);
  unsigned short* WtCl = (unsigned short*)alloc((size_t)64 * 512 * 2);
  unsigned short* mbuf = (unsigned short*)alloc((size_t)Nn * Hd * 2);
  unsigned short* mcls = (unsigned short*)alloc((size_t)Nn * Cd * 2);
  unsigned short* comb = (unsigned short*)alloc((size_t)Nn * 512 * 2);

  // ---- CSR build (3-level parallel scan)
  k_zero<<<(Nn + 255) / 256, 256, 0, stream>>>(cnt);
  k_count<<<(Ne + 255) / 256, 256, 0, stream>>>(dst, cnt);
  k_partial<<<NB, 256, 0, stream>>>(cnt, partial);
  k_scan_small<<<1, 256, 0, stream>>>(partial, poffs, rowptr);
  k_rowptr<<<NB, 256, 0, stream>>>(cnt, poffs, rowptr, cursor, dinv);
  k_fill<<<(Ne + Nn + 255) / 256, 256, 0, stream>>>(src, dst, dinv, cursor, csrs, csrn);

  // ---- weights: transpose + bf16
  auto wt = [&](const float* W, unsigned short* Wt, int K, int H, int Hpad) {
    k_wt<<<(Hpad * K + 255) / 256, 256, 0, stream>>>(W, Wt, K, H, Hpad);
  };
  wt(convW[0], WtC0, 128, 256, 256);
  wt(convW[1], WtC1, 512, 256, 256);
  wt(convW[2], WtC2, 512, 256, 256);
  wt(linW[0], WtL0, 128, 256, 256);
  wt(linW[1], WtL1, 256, 256, 256);
  wt(linW[2], WtL2, 512, 256, 256);
  wt(clsW, WtCl, 512, 40, 64);

  const int GM = (Nn + 63) / 64;    // 782 blocks, BM=64 BN=256
  const int GC = (Nn + 255) / 256;  // 196 blocks, BM=256 BN=64 (cls)
  const int GB = (Nn * 64) / 256;   // 12500 blocks, one wave per node

  // ---- layer 0
  k_gemm<1, 4><<<GM, 256, 0, stream>>>(x, 0, 128, WtC0, nullptr, nullptr, mbuf, Hd, 0, 256, 0);
  k_gemm<1, 4><<<GM, 256, 0, stream>>>(feature, 0, 128, WtL0, nullptr, linB[0], comb, 512, 0, 256, 1);
  k_gather<<<GB, 256, 0, stream>>>(mbuf, rowptr, csrs, csrn, convB[0], comb, 512, 256);
  // ---- layer 1
  k_gemm<0, 4><<<GM, 256, 0, stream>>>(comb, 512, 512, WtC1, nullptr, nullptr, mbuf, Hd, 0, 256, 0);
  k_gemm<1, 4><<<GM, 256, 0, stream>>>(feature + (size_t)1 * Nn * Fd, 0, 256, WtL1, oweights, linB[1], comb, 512, 0, 256, 1);
  k_gather<<<GB, 256, 0, stream>>>(mbuf, rowptr, csrs, csrn, convB[1], comb, 512, 256);
  // ---- layer 2
  k_gemm<0, 4><<<GM, 256, 0, stream>>>(comb, 512, 512, WtC2, nullptr, nullptr, mbuf, Hd, 0, 256, 0);
  k_gemm<1, 4><<<GM, 256, 0, stream>>>(feature + (size_t)3 * Nn * Fd, 0, 512, WtL2, oweights, linB[2], comb, 512, 0, 256, 1);
  k_gather<<<GB, 256, 0, stream>>>(mbuf, rowptr, csrs, csrn, convB[2], comb, 512, 256);
  // ---- classifier
  k_gemm<0, 1><<<GC, 256, 0, stream>>>(comb, 512, 512, WtCl, nullptr, nullptr, mcls, Cd, 0, 40, 0);
  k_gcls<<<GB, 256, 0, stream>>>(mcls, rowptr, csrs, csrn, clsB, out);
}

// Round 4
// 679.560 us; speedup vs baseline: 1.0490x; 1.0490x over previous
//
#include <hip/hip_runtime.h>

#define DEVI __device__ __forceinline__

namespace {

constexpr int Nn = 50000;   // nodes
constexpr int Ne = 800000;  // edges
constexpr int Fd = 128;     // feature dim
constexpr int Hd = 256;     // hidden
constexpr int Cd = 40;      // classes
constexpr int NB = (Nn + 255) / 256;  // 196 scan blocks

typedef __attribute__((ext_vector_type(8))) short s16x8;   // 8 bf16 (4 VGPR) MFMA frag
typedef __attribute__((ext_vector_type(8))) unsigned short u16x8;
typedef __attribute__((ext_vector_type(4))) float f32x4;

DEVI unsigned short f2bf(float f) {
  unsigned int u = __builtin_bit_cast(unsigned int, f);
  u += 0x7fffu + ((u >> 16) & 1u);   // RNE
  return (unsigned short)(u >> 16);
}
DEVI float bf2f(unsigned short s) {
  return __builtin_bit_cast(float, ((unsigned int)s) << 16);
}

// ---------------- CSR build ----------------
__global__ void k_zero(int* cnt) {
  int i = blockIdx.x * 256 + threadIdx.x;
  if (i < Nn) cnt[i] = 0;
}

__global__ void k_count(const int* __restrict__ dst, int* __restrict__ cnt) {
  int e = blockIdx.x * 256 + threadIdx.x;
  if (e < Ne) atomicAdd(&cnt[dst[e]], 1);
}

// level 1: per-block sums of (cnt[i]+1)
__global__ __launch_bounds__(256) void k_partial(const int* __restrict__ cnt,
                                                 int* __restrict__ partial) {
  __shared__ int red[256];
  const int t = threadIdx.x;
  const int i = blockIdx.x * 256 + t;
  red[t] = (i < Nn) ? cnt[i] + 1 : 0;
  __syncthreads();
#pragma unroll
  for (int off = 128; off; off >>= 1) {
    if (t < off) red[t] += red[t + off];
    __syncthreads();
  }
  if (t == 0) partial[blockIdx.x] = red[0];
}

// level 2: scan the 196 partials (tiny, one block)
__global__ __launch_bounds__(256) void k_scan_small(const int* __restrict__ partial,
                                                    int* __restrict__ poffs,
                                                    int* __restrict__ rowptr) {
  __shared__ int s[256];
  const int t = threadIdx.x;
  const int v = (t < NB) ? partial[t] : 0;
  s[t] = v;
  __syncthreads();
#pragma unroll
  for (int off = 1; off < 256; off <<= 1) {
    int add = (t >= off) ? s[t - off] : 0;
    __syncthreads();
    s[t] += add;
    __syncthreads();
  }
  if (t < NB) poffs[t] = s[t] - v;        // exclusive
  if (t == NB - 1) rowptr[Nn] = s[t];     // total = Ne + Nn
}

// level 3: per-block scan + offset -> rowptr / cursor / dinv
__global__ __launch_bounds__(256) void k_rowptr(const int* __restrict__ cnt,
                                                const int* __restrict__ poffs,
                                                int* __restrict__ rowptr,
                                                int* __restrict__ cursor,
                                                float* __restrict__ dinv) {
  __shared__ int s[256];
  const int t = threadIdx.x;
  const int i = blockIdx.x * 256 + t;
  const int c = (i < Nn) ? cnt[i] + 1 : 0;
  s[t] = c;
  __syncthreads();
#pragma unroll
  for (int off = 1; off < 256; off <<= 1) {
    int add = (t >= off) ? s[t - off] : 0;
    __syncthreads();
    s[t] += add;
    __syncthreads();
  }
  if (i < Nn) {
    const int excl = s[t] - c + poffs[blockIdx.x];
    rowptr[i] = excl;
    cursor[i] = excl;
    dinv[i] = rsqrtf((float)c);
  }
}

__global__ void k_fill(const int* __restrict__ src, const int* __restrict__ dst,
                       const float* __restrict__ dinv, int* __restrict__ cursor,
                       int* __restrict__ csrs, float* __restrict__ csrn) {
  int e = blockIdx.x * 256 + threadIdx.x;
  if (e < Ne) {
    int s = src[e], d = dst[e];
    int pos = atomicAdd(&cursor[d], 1);
    csrs[pos] = s;
    csrn[pos] = dinv[s] * dinv[d];
  } else if (e < Ne + Nn) {
    int d = e - Ne;  // self loop
    int pos = atomicAdd(&cursor[d], 1);
    csrs[pos] = d;
    float v = dinv[d];
    csrn[pos] = v * v;
  }
}

// ---------------- weight transpose + bf16 cast: Wt[c][k] = W[k][c] ----------------
__global__ void k_wt(const float* __restrict__ W, unsigned short* __restrict__ Wt,
                     int K, int H, int Hpad) {
  int idx = blockIdx.x * 256 + threadIdx.x;
  if (idx >= Hpad * K) return;
  int c = idx / K, k = idx - c * K;
  float v = (c < H) ? W[(size_t)k * H + c] : 0.0f;
  Wt[idx] = f2bf(v);
}

// ---------------- GEMM: C[M x ncols] = A[M x K] @ W, bf16 MFMA ----------------
// Single col-pass: BN = NWC*64 (grid.y == 1), BM = (4/NWC)*64. 4 waves.
// MODE 0: A = bf16 row-major (lda elems)
// MODE 1: A(r,k) = feat[(k>>7)*Nn*Fd + r*Fd + (k&127)] * (ow ? ow[(k>>7)&1] : 1)  (f32 source)
template <int MODE, int NWC>
__global__ __launch_bounds__(256) void k_gemm(
    const void* __restrict__ Aptr, int lda, int K,
    const unsigned short* __restrict__ Wt,  // [BN][K] bf16 (padded)
    const float* __restrict__ ow, const float* __restrict__ bias,
    unsigned short* __restrict__ Cout, int ldc, int col_off, int ncols, int relu) {
  constexpr int WRN = 4 / NWC;
  constexpr int BM = WRN * 64;
  constexpr int BN = NWC * 64;
  constexpr int APT = BM / 32;  // vec8s per thread for A tile
  constexpr int BPT = BN / 32;  // vec8s per thread for B tile
  __shared__ short lA[BM * 64];
  __shared__ short lB[BN * 64];
  const int tid = threadIdx.x;
  const int lane = tid & 63;
  const int wid = tid >> 6;
  const int wr = wid / NWC;
  const int wc = wid % NWC;
  const int row0 = blockIdx.x * BM;

  f32x4 acc[4][4];
#pragma unroll
  for (int i = 0; i < 4; ++i)
#pragma unroll
    for (int j = 0; j < 4; ++j) acc[i][j] = (f32x4)0.0f;

  const s16x8 VZ = (s16x8)0;
  const int nkt = K >> 6;
  for (int kt = 0; kt < nkt; ++kt) {
    const int k0 = kt * 64;
    // ---- stage A tile (BM x 64 bf16), XOR-swizzled
#pragma unroll
    for (int i = 0; i < APT; ++i) {
      const int v = tid * APT + i;
      const int row = v >> 3;      // 0..BM-1
      const int c16 = v & 7;       // vec8 within row
      const int grow = row0 + row;
      const bool rv = grow < Nn;
      s16x8 val;
      if (MODE == 0) {
        const unsigned short* A = (const unsigned short*)Aptr;
        val = rv ? *(const s16x8*)(A + (size_t)grow * lda + k0 + c16 * 8) : VZ;
      } else {
        const float* feat = (const float*)Aptr;
        const int c = k0 >> 7;
        const float scale = ow ? ow[c & 1] : 1.0f;
        const float* p = feat + (size_t)c * ((size_t)Nn * Fd) + (size_t)grow * Fd +
                         (k0 & 127) + c16 * 8;
        f32x4 a = rv ? *(const f32x4*)p : (f32x4)0.0f;
        f32x4 b = rv ? *(const f32x4*)(p + 4) : (f32x4)0.0f;
#pragma unroll
        for (int q = 0; q < 4; ++q) val[q] = (short)f2bf(a[q] * scale);
#pragma unroll
        for (int q = 0; q < 4; ++q) val[4 + q] = (short)f2bf(b[q] * scale);
      }
      int byte = row * 128 + c16 * 16;
      byte ^= (row & 7) << 4;
      *(s16x8*)((char*)lA + byte) = val;
    }
    // ---- stage B tile (BN x 64 bf16) from pre-transposed Wt
#pragma unroll
    for (int i = 0; i < BPT; ++i) {
      const int v = tid * BPT + i;
      const int row = v >> 3;
      const int c16 = v & 7;
      s16x8 val = *(const s16x8*)(Wt + (size_t)row * K + k0 + c16 * 8);
      int byte = row * 128 + c16 * 16;
      byte ^= (row & 7) << 4;
      *(s16x8*)((char*)lB + byte) = val;
    }
    __syncthreads();
    // ---- compute: 2 k-slices of 32, 4x4 frags per wave
#pragma unroll
    for (int kk = 0; kk < 2; ++kk) {
      s16x8 af[4], bv[4];
#pragma unroll
      for (int mi = 0; mi < 4; ++mi) {
        int r = wr * 64 + mi * 16 + (lane & 15);
        int byte = r * 128 + kk * 64 + (lane >> 4) * 16;
        byte ^= (r & 7) << 4;
        af[mi] = *(const s16x8*)((const char*)lA + byte);
      }
#pragma unroll
      for (int ni = 0; ni < 4; ++ni) {
        int c = wc * 64 + ni * 16 + (lane & 15);
        int byte = c * 128 + kk * 64 + (lane >> 4) * 16;
        byte ^= (c & 7) << 4;
        bv[ni] = *(const s16x8*)((const char*)lB + byte);
      }
#pragma unroll
      for (int mi = 0; mi < 4; ++mi)
#pragma unroll
        for (int ni = 0; ni < 4; ++ni)
          acc[mi][ni] = __builtin_amdgcn_mfma_f32_16x16x32_bf16(af[mi], bv[ni], acc[mi][ni], 0, 0, 0);
    }
    __syncthreads();
  }

  // ---- epilogue: bias / relu / bf16 store
#pragma unroll
  for (int ni = 0; ni < 4; ++ni) {
    const int col = wc * 64 + ni * 16 + (lane & 15);
    if (col >= ncols) continue;
    const float bvl = bias ? bias[col] : 0.0f;
#pragma unroll
    for (int mi = 0; mi < 4; ++mi) {
      const int rb = row0 + wr * 64 + mi * 16 + ((lane >> 4) << 2);
#pragma unroll
      for (int q = 0; q < 4; ++q) {
        int r = rb + q;
        if (r < Nn) {
          float vv = acc[mi][ni][q] + bvl;
          if (relu) vv = fmaxf(vv, 0.0f);
          Cout[(size_t)r * ldc + col_off + col] = f2bf(vv);
        }
      }
    }
  }
}

// ---------------- gather (aggregate) 256-dim: one wave per node ----------------
// 2 edges per vmem instruction: half = lane>>5 picks even/odd edge of a pair,
// each 32-lane half loads a FULL 256-dim bf16 row as ushort8 (16 B/lane).
// Halves keep independent accumulators; one shfl_xor(32) pass merges.
__global__ __launch_bounds__(256) void k_gather(
    const unsigned short* __restrict__ m, const int* __restrict__ rowptr,
    const int* __restrict__ csrs, const float* __restrict__ csrn,
    const float* __restrict__ bias, unsigned short* __restrict__ outp,
    int ldc, int col_off) {
  const int wid = (blockIdx.x * 256 + threadIdx.x) >> 6;
  const int lane = threadIdx.x & 63;
  if (wid >= Nn) return;
  const int half = lane >> 5;
  const int sub = lane & 31;          // owns dims [sub*8, sub*8+8)
  const int e0 = rowptr[wid], e1 = rowptr[wid + 1];
  const unsigned short* mcol = m + sub * 8;
  float acc[8];
#pragma unroll
  for (int q = 0; q < 8; ++q) acc[q] = 0.f;

  for (int base = e0; base < e1; base += 64) {
    const int idx = base + lane;
    int s_ = 0;
    float w_ = 0.f;   // lanes past e1 contribute weight 0 (and row 0, harmless)
    if (idx < e1) { s_ = csrs[idx]; w_ = csrn[idx]; }
    const int cn = min(64, e1 - base);
    const int npair = (cn + 1) >> 1;
    // depth-2 pipeline over edge pairs (4 edges in flight per wave)
    int sA = __shfl(s_, half);
    float wA = __shfl(w_, half);
    u16x8 vA = *(const u16x8*)(mcol + (size_t)sA * Hd);
    for (int jj = 1; jj < npair; ++jj) {
      const int j = 2 * jj + half;
      const int sB = __shfl(s_, j);
      const float wB = __shfl(w_, j);
      const u16x8 vB = *(const u16x8*)(mcol + (size_t)sB * Hd);
#pragma unroll
      for (int q = 0; q < 8; ++q) acc[q] += wA * bf2f(vA[q]);
      wA = wB; vA = vB;
    }
#pragma unroll
    for (int q = 0; q < 8; ++q) acc[q] += wA * bf2f(vA[q]);
  }

#pragma unroll
  for (int q = 0; q < 8; ++q) acc[q] += __shfl_xor(acc[q], 32);
  if (half == 0) {
    u16x8 o;
#pragma unroll
    for (int q = 0; q < 8; ++q) {
      float v = fmaxf(acc[q] + bias[sub * 8 + q], 0.f);
      o[q] = f2bf(v);
    }
    *(u16x8*)(outp + (size_t)wid * ldc + col_off + sub * 8) = o;
  }
}

// ---------------- cls gather + bias + log_softmax (40 dims) ----------------
// Same pair structure; only sub<5 lanes carry data (5 x 8 dims = 40).
__global__ __launch_bounds__(256) void k_gcls(
    const unsigned short* __restrict__ mc, const int* __restrict__ rowptr,
    const int* __restrict__ csrs, const float* __restrict__ csrn,
    const float* __restrict__ clsb, float* __restrict__ outp) {
  const int wid = (blockIdx.x * 256 + threadIdx.x) >> 6;
  const int lane = threadIdx.x & 63;
  if (wid >= Nn) return;
  const int half = lane >> 5;
  const int sub = lane & 31;
  const bool act = sub < 5;
  const int e0 = rowptr[wid], e1 = rowptr[wid + 1];
  float acc[8];
#pragma unroll
  for (int q = 0; q < 8; ++q) acc[q] = 0.f;

  for (int base = e0; base < e1; base += 64) {
    const int idx = base + lane;
    int s_ = 0;
    float w_ = 0.f;
    if (idx < e1) { s_ = csrs[idx]; w_ = csrn[idx]; }
    const int cn = min(64, e1 - base);
    const int npair = (cn + 1) >> 1;
    int sA = __shfl(s_, half);
    float wA = __shfl(w_, half);
    u16x8 vA = act ? *(const u16x8*)(mc + (size_t)sA * Cd + sub * 8) : (u16x8)0;
    for (int jj = 1; jj < npair; ++jj) {
      const int j = 2 * jj + half;
      const int sB = __shfl(s_, j);
      const float wB = __shfl(w_, j);
      const u16x8 vB = act ? *(const u16x8*)(mc + (size_t)sB * Cd + sub * 8) : (u16x8)0;
#pragma unroll
      for (int q = 0; q < 8; ++q) acc[q] += wA * bf2f(vA[q]);
      wA = wB; vA = vB;
    }
#pragma unroll
    for (int q = 0; q < 8; ++q) acc[q] += wA * bf2f(vA[q]);
  }

#pragma unroll
  for (int q = 0; q < 8; ++q) acc[q] += __shfl_xor(acc[q], 32);

  float l[8];
  float mx = -3.4e38f;
  if (act) {
#pragma unroll
    for (int q = 0; q < 8; ++q) {
      l[q] = acc[q] + clsb[sub * 8 + q];
      mx = fmaxf(mx, l[q]);
    }
  }
  // reduce over the 8-lane group (lanes 0..7 cover subs 0..7; subs 5..7 neutral)
#pragma unroll
  for (int off = 1; off < 8; off <<= 1) mx = fmaxf(mx, __shfl_xor(mx, off));
  float se = 0.f;
  if (act) {
#pragma unroll
    for (int q = 0; q < 8; ++q) se += expf(l[q] - mx);
  }
#pragma unroll
  for (int off = 1; off < 8; off <<= 1) se += __shfl_xor(se, off);
  const float lse = mx + logf(se);
  if (half == 0 && act) {
    float* o1 = outp + (size_t)wid * Cd + sub * 8;
    float* o2 = o1 + (size_t)Nn * Cd;
#pragma unroll
    for (int q = 0; q < 8; ++q) {
      o1[q] = l[q] - lse;
      o2[q] = l[q];
    }
  }
}

}  // namespace

extern "C" void kernel_launch(void* const* d_in, const int* in_sizes, int n_in,
                              void* d_out, int out_size, void* d_ws, size_t ws_size,
                              hipStream_t stream) {
  (void)in_sizes; (void)n_in; (void)out_size; (void)ws_size;
  const float* x       = (const float*)d_in[0];
  const float* feature = (const float*)d_in[1];
  const int* src       = (const int*)d_in[2];
  const int* dst       = (const int*)d_in[3];
  const float* convW[3] = {(const float*)d_in[4], (const float*)d_in[6], (const float*)d_in[8]};
  const float* convB[3] = {(const float*)d_in[5], (const float*)d_in[7], (const float*)d_in[9]};
  const float* linW[3]  = {(const float*)d_in[10], (const float*)d_in[12], (const float*)d_in[14]};
  const float* linB[3]  = {(const float*)d_in[11], (const float*)d_in[13], (const float*)d_in[15]};
  const float* oweights = (const float*)d_in[16];
  const float* clsW     = (const float*)d_in[17];
  const float* clsB     = (const float*)d_in[18];
  float* out = (float*)d_out;

  char* wsp = (char*)d_ws;
  auto alloc = [&](size_t bytes) -> void* {
    void* p = wsp;
    wsp += (bytes + 255) & ~(size_t)255;
    return p;
  };
  int* cnt      = (int*)alloc((size_t)Nn * 4);
  int* cursor   = (int*)alloc((size_t)Nn * 4);
  int* rowptr   = (int*)alloc((size_t)(Nn + 1) * 4);
  float* dinv   = (float*)alloc((size_t)Nn * 4);
  int* partial  = (int*)alloc((size_t)NB * 4);
  int* poffs    = (int*)alloc((size_t)NB * 4);
  int* csrs     = (int*)alloc((size_t)(Ne + Nn) * 4);
  float* csrn   = (float*)alloc((size_t)(Ne + Nn) * 4);
  unsigned short* WtC0 = (unsigned short*)alloc((size_t)256 * 128 * 2);
  unsigned short* WtC1 = (unsigned short*)alloc((size_t)256 * 512 * 2);
  unsigned short* WtC2 = (unsigned short*)alloc((size_t)256 * 512 * 2);
  unsigned short* WtL0 = (unsigned short*)alloc((size_t)256 * 128 * 2);
  unsigned short* WtL1 = (unsigned short*)alloc((size_t)256 * 256 * 2);
  unsigned short* WtL2 = (unsigned short*)alloc((size_t)256 * 512 * 2);
  unsigned short* WtCl = (unsigned short*)alloc((size_t)64 * 512 * 2);
  unsigned short* mbuf = (unsigned short*)alloc((size_t)Nn * Hd * 2);
  unsigned short* mcls = (unsigned short*)alloc((size_t)Nn * Cd * 2);
  unsigned short* comb = (unsigned short*)alloc((size_t)Nn * 512 * 2);

  // ---- CSR build (3-level parallel scan)
  k_zero<<<(Nn + 255) / 256, 256, 0, stream>>>(cnt);
  k_count<<<(Ne + 255) / 256, 256, 0, stream>>>(dst, cnt);
  k_partial<<<NB, 256, 0, stream>>>(cnt, partial);
  k_scan_small<<<1, 256, 0, stream>>>(partial, poffs, rowptr);
  k_rowptr<<<NB, 256, 0, stream>>>(cnt, poffs, rowptr, cursor, dinv);
  k_fill<<<(Ne + Nn + 255) / 256, 256, 0, stream>>>(src, dst, dinv, cursor, csrs, csrn);

  // ---- weights: transpose + bf16
  auto wt = [&](const float* W, unsigned short* Wt, int K, int H, int Hpad) {
    k_wt<<<(Hpad * K + 255) / 256, 256, 0, stream>>>(W, Wt, K, H, Hpad);
  };
  wt(convW[0], WtC0, 128, 256, 256);
  wt(convW[1], WtC1, 512, 256, 256);
  wt(convW[2], WtC2, 512, 256, 256);
  wt(linW[0], WtL0, 128, 256, 256);
  wt(linW[1], WtL1, 256, 256, 256);
  wt(linW[2], WtL2, 512, 256, 256);
  wt(clsW, WtCl, 512, 40, 64);

  const int GM = (Nn + 63) / 64;    // 782 blocks, BM=64 BN=256
  const int GC = (Nn + 255) / 256;  // 196 blocks, BM=256 BN=64 (cls)
  const int GB = (Nn * 64) / 256;   // 12500 blocks, one wave per node

  // ---- layer 0
  k_gemm<1, 4><<<GM, 256, 0, stream>>>(x, 0, 128, WtC0, nullptr, nullptr, mbuf, Hd, 0, 256, 0);
  k_gemm<1, 4><<<GM, 256, 0, stream>>>(feature, 0, 128, WtL0, nullptr, linB[0], comb, 512, 0, 256, 1);
  k_gather<<<GB, 256, 0, stream>>>(mbuf, rowptr, csrs, csrn, convB[0], comb, 512, 256);
  // ---- layer 1
  k_gemm<0, 4><<<GM, 256, 0, stream>>>(comb, 512, 512, WtC1, nullptr, nullptr, mbuf, Hd, 0, 256, 0);
  k_gemm<1, 4><<<GM, 256, 0, stream>>>(feature + (size_t)1 * Nn * Fd, 0, 256, WtL1, oweights, linB[1], comb, 512, 0, 256, 1);
  k_gather<<<GB, 256, 0, stream>>>(mbuf, rowptr, csrs, csrn, convB[1], comb, 512, 256);
  // ---- layer 2
  k_gemm<0, 4><<<GM, 256, 0, stream>>>(comb, 512, 512, WtC2, nullptr, nullptr, mbuf, Hd, 0, 256, 0);
  k_gemm<1, 4><<<GM, 256, 0, stream>>>(feature + (size_t)3 * Nn * Fd, 0, 512, WtL2, oweights, linB[2], comb, 512, 0, 256, 1);
  k_gather<<<GB, 256, 0, stream>>>(mbuf, rowptr, csrs, csrn, convB[2], comb, 512, 256);
  // ---- classifier
  k_gemm<0, 1><<<GC, 256, 0, stream>>>(comb, 512, 512, WtCl, nullptr, nullptr, mcls, Cd, 0, 40, 0);
  k_gcls<<<GB, 256, 0, stream>>>(mcls, rowptr, csrs, csrn, clsB, out);
}

// Round 5
// 619.624 us; speedup vs baseline: 1.1504x; 1.0967x over previous
//
#include <hip/hip_runtime.h>

#define DEVI __device__ __forceinline__

namespace {

constexpr int Nn = 50000;   // nodes
constexpr int Ne = 800000;  // edges
constexpr int Fd = 128;     // feature dim
constexpr int Hd = 256;     // hidden
constexpr int Cd = 40;      // classes
constexpr int NB = (Nn + 255) / 256;  // 196 scan blocks

typedef __attribute__((ext_vector_type(8))) short s16x8;   // 8 bf16 (4 VGPR) MFMA frag
typedef __attribute__((ext_vector_type(8))) unsigned short u16x8;
typedef __attribute__((ext_vector_type(4))) float f32x4;

DEVI unsigned short f2bf(float f) {
  unsigned int u = __builtin_bit_cast(unsigned int, f);
  u += 0x7fffu + ((u >> 16) & 1u);   // RNE
  return (unsigned short)(u >> 16);
}
DEVI float bf2f(unsigned short s) {
  return __builtin_bit_cast(float, ((unsigned int)s) << 16);
}

// Direct HBM->LDS 16B/lane load (CK-style): M0 = wave-uniform LDS byte base,
// HW writes LDS at M0 + lane*16. gptr is per-lane.
DEVI void gld_lds16(const void* gptr, void* lds_base) {
  const unsigned m0v =
      (unsigned)__builtin_amdgcn_readfirstlane((unsigned)(uintptr_t)lds_base);
  asm volatile("s_mov_b32 m0, %0\n\t"
               "global_load_lds_dwordx4 %1, off"
               :: "s"(m0v), "v"(gptr) : "memory");
}

// ---------------- CSR build ----------------
__global__ void k_zero(int* cnt) {
  int i = blockIdx.x * 256 + threadIdx.x;
  if (i < Nn) cnt[i] = 0;
}

__global__ void k_count(const int* __restrict__ dst, int* __restrict__ cnt) {
  int e = blockIdx.x * 256 + threadIdx.x;
  if (e < Ne) atomicAdd(&cnt[dst[e]], 1);
}

// level 1: per-block sums of (cnt[i]+1)
__global__ __launch_bounds__(256) void k_partial(const int* __restrict__ cnt,
                                                 int* __restrict__ partial) {
  __shared__ int red[256];
  const int t = threadIdx.x;
  const int i = blockIdx.x * 256 + t;
  red[t] = (i < Nn) ? cnt[i] + 1 : 0;
  __syncthreads();
#pragma unroll
  for (int off = 128; off; off >>= 1) {
    if (t < off) red[t] += red[t + off];
    __syncthreads();
  }
  if (t == 0) partial[blockIdx.x] = red[0];
}

// level 2: scan the 196 partials (tiny, one block)
__global__ __launch_bounds__(256) void k_scan_small(const int* __restrict__ partial,
                                                    int* __restrict__ poffs,
                                                    int* __restrict__ rowptr) {
  __shared__ int s[256];
  const int t = threadIdx.x;
  const int v = (t < NB) ? partial[t] : 0;
  s[t] = v;
  __syncthreads();
#pragma unroll
  for (int off = 1; off < 256; off <<= 1) {
    int add = (t >= off) ? s[t - off] : 0;
    __syncthreads();
    s[t] += add;
    __syncthreads();
  }
  if (t < NB) poffs[t] = s[t] - v;        // exclusive
  if (t == NB - 1) rowptr[Nn] = s[t];     // total = Ne + Nn
}

// level 3: per-block scan + offset -> rowptr / cursor / dinv
__global__ __launch_bounds__(256) void k_rowptr(const int* __restrict__ cnt,
                                                const int* __restrict__ poffs,
                                                int* __restrict__ rowptr,
                                                int* __restrict__ cursor,
                                                float* __restrict__ dinv) {
  __shared__ int s[256];
  const int t = threadIdx.x;
  const int i = blockIdx.x * 256 + t;
  const int c = (i < Nn) ? cnt[i] + 1 : 0;
  s[t] = c;
  __syncthreads();
#pragma unroll
  for (int off = 1; off < 256; off <<= 1) {
    int add = (t >= off) ? s[t - off] : 0;
    __syncthreads();
    s[t] += add;
    __syncthreads();
  }
  if (i < Nn) {
    const int excl = s[t] - c + poffs[blockIdx.x];
    rowptr[i] = excl;
    cursor[i] = excl;
    dinv[i] = rsqrtf((float)c);
  }
}

__global__ void k_fill(const int* __restrict__ src, const int* __restrict__ dst,
                       const float* __restrict__ dinv, int* __restrict__ cursor,
                       int* __restrict__ csrs, float* __restrict__ csrn) {
  int e = blockIdx.x * 256 + threadIdx.x;
  if (e < Ne) {
    int s = src[e], d = dst[e];
    int pos = atomicAdd(&cursor[d], 1);
    csrs[pos] = s;
    csrn[pos] = dinv[s] * dinv[d];
  } else if (e < Ne + Nn) {
    int d = e - Ne;  // self loop
    int pos = atomicAdd(&cursor[d], 1);
    csrs[pos] = d;
    float v = dinv[d];
    csrn[pos] = v * v;
  }
}

// ---------------- weight transpose + bf16 cast + PRE-SWIZZLE ----------------
// WtS[c][kt*64 + c16*8 + j] = W[(kt*64 + (c16 ^ (c&7))*8 + j)][c]
// so a LINEAR global_load_lds produces the XOR-swizzled LDS image.
__global__ void k_wt(const float* __restrict__ W, unsigned short* __restrict__ Wt,
                     int K, int H, int Hpad) {
  int idx = blockIdx.x * 256 + threadIdx.x;
  if (idx >= Hpad * K) return;
  int c = idx / K, k = idx - c * K;
  int kt = k >> 6, c16 = (k >> 3) & 7, j = k & 7;
  int ksrc = (kt << 6) | ((c16 ^ (c & 7)) << 3) | j;
  float v = (c < H) ? W[(size_t)ksrc * H + c] : 0.0f;
  Wt[idx] = f2bf(v);
}

// ---------------- GEMM: C[M x ncols] = A[M x K] @ W, bf16 MFMA ----------------
// BN = NWC*64, BM = (4/NWC)*64, 4 waves, single col-pass.
// MODE 0: A = bf16 row-major, direct global_load_lds (A MUST be row-padded past grid!)
// MODE 1: A(r,k) = feat[(k>>7)*Nn*Fd + r*Fd + (k&127)] * (ow ? ow[(k>>7)&1] : 1), reg-staged
// B (WtS) is pre-swizzled; always direct global_load_lds.
template <int MODE, int NWC>
__global__ __launch_bounds__(256) void k_gemm(
    const void* __restrict__ Aptr, int lda, int K,
    const unsigned short* __restrict__ Wt,  // [BN][K] bf16 pre-swizzled
    const float* __restrict__ ow, const float* __restrict__ bias,
    unsigned short* __restrict__ Cout, int ldc, int col_off, int ncols, int relu) {
  constexpr int WRN = 4 / NWC;
  constexpr int BM = WRN * 64;
  constexpr int BN = NWC * 64;
  constexpr int AISSW = BM / 32;  // global_load_lds issues per wave (A)
  constexpr int BISSW = BN / 32;  // issues per wave (B)
  constexpr int APT = BM / 32;    // vec8s per thread (A, MODE 1 reg path)
  __shared__ short lA[BM * 64];
  __shared__ short lB[BN * 64];
  const int tid = threadIdx.x;
  const int lane = tid & 63;
  const int wid = tid >> 6;
  const int wr = wid / NWC;
  const int wc = wid % NWC;
  const int row0 = blockIdx.x * BM;

  f32x4 acc[4][4];
#pragma unroll
  for (int i = 0; i < 4; ++i)
#pragma unroll
    for (int j = 0; j < 4; ++j) acc[i][j] = (f32x4)0.0f;

  // per-lane source-swizzle chunk for A direct loads:
  // LDS slot (row=l>>3, c16=l&7) must hold global chunk (l&7)^((l>>3)&7)
  const int c16a = (lane & 7) ^ ((lane >> 3) & 7);

  const int nkt = K >> 6;
  for (int kt = 0; kt < nkt; ++kt) {
    const int k0 = kt * 64;
    // ---- stage A tile (BM x 64 bf16)
    if (MODE == 0) {
      const unsigned short* A = (const unsigned short*)Aptr;
#pragma unroll
      for (int i = 0; i < AISSW; ++i) {
        const int iss = wid * AISSW + i;
        const int row = row0 + iss * 8 + (lane >> 3);
        gld_lds16(A + (size_t)row * lda + k0 + c16a * 8,
                  (char*)lA + iss * 1024);
      }
    } else {
#pragma unroll
      for (int i = 0; i < APT; ++i) {
        const int v = tid * APT + i;
        const int row = v >> 3;      // 0..BM-1
        const int c16 = v & 7;       // vec8 within row
        const int grow = row0 + row;
        const bool rv = grow < Nn;
        const float* feat = (const float*)Aptr;
        const int c = k0 >> 7;
        const float scale = ow ? ow[c & 1] : 1.0f;
        const float* p = feat + (size_t)c * ((size_t)Nn * Fd) + (size_t)grow * Fd +
                         (k0 & 127) + c16 * 8;
        f32x4 a = rv ? *(const f32x4*)p : (f32x4)0.0f;
        f32x4 b = rv ? *(const f32x4*)(p + 4) : (f32x4)0.0f;
        s16x8 val;
#pragma unroll
        for (int q = 0; q < 4; ++q) val[q] = (short)f2bf(a[q] * scale);
#pragma unroll
        for (int q = 0; q < 4; ++q) val[4 + q] = (short)f2bf(b[q] * scale);
        int byte = row * 128 + c16 * 16;
        byte ^= (row & 7) << 4;
        *(s16x8*)((char*)lA + byte) = val;
      }
    }
    // ---- stage B tile (BN x 64 bf16), pre-swizzled source -> linear direct load
#pragma unroll
    for (int i = 0; i < BISSW; ++i) {
      const int iss = wid * BISSW + i;
      const int col = iss * 8 + (lane >> 3);
      gld_lds16(Wt + (size_t)col * K + k0 + (lane & 7) * 8,
                (char*)lB + iss * 1024);
    }
    asm volatile("s_waitcnt vmcnt(0)" ::: "memory");
    __syncthreads();
    // ---- compute: 2 k-slices of 32, 4x4 frags per wave
#pragma unroll
    for (int kk = 0; kk < 2; ++kk) {
      s16x8 af[4], bv[4];
#pragma unroll
      for (int mi = 0; mi < 4; ++mi) {
        int r = wr * 64 + mi * 16 + (lane & 15);
        int byte = r * 128 + kk * 64 + (lane >> 4) * 16;
        byte ^= (r & 7) << 4;
        af[mi] = *(const s16x8*)((const char*)lA + byte);
      }
#pragma unroll
      for (int ni = 0; ni < 4; ++ni) {
        int c = wc * 64 + ni * 16 + (lane & 15);
        int byte = c * 128 + kk * 64 + (lane >> 4) * 16;
        byte ^= (c & 7) << 4;
        bv[ni] = *(const s16x8*)((const char*)lB + byte);
      }
#pragma unroll
      for (int mi = 0; mi < 4; ++mi)
#pragma unroll
        for (int ni = 0; ni < 4; ++ni)
          acc[mi][ni] = __builtin_amdgcn_mfma_f32_16x16x32_bf16(af[mi], bv[ni], acc[mi][ni], 0, 0, 0);
    }
    __syncthreads();
  }

  // ---- epilogue: bias / relu / bf16 store
#pragma unroll
  for (int ni = 0; ni < 4; ++ni) {
    const int col = wc * 64 + ni * 16 + (lane & 15);
    if (col >= ncols) continue;
    const float bvl = bias ? bias[col] : 0.0f;
#pragma unroll
    for (int mi = 0; mi < 4; ++mi) {
      const int rb = row0 + wr * 64 + mi * 16 + ((lane >> 4) << 2);
#pragma unroll
      for (int q = 0; q < 4; ++q) {
        int r = rb + q;
        if (r < Nn) {
          float vv = acc[mi][ni][q] + bvl;
          if (relu) vv = fmaxf(vv, 0.0f);
          Cout[(size_t)r * ldc + col_off + col] = f2bf(vv);
        }
      }
    }
  }
}

// ---------------- gather (aggregate) 256-dim: one wave per node ----------------
// 2 edges per vmem instruction: half = lane>>5 picks even/odd edge of a pair,
// each 32-lane half loads a FULL 256-dim bf16 row as ushort8 (16 B/lane).
__global__ __launch_bounds__(256) void k_gather(
    const unsigned short* __restrict__ m, const int* __restrict__ rowptr,
    const int* __restrict__ csrs, const float* __restrict__ csrn,
    const float* __restrict__ bias, unsigned short* __restrict__ outp,
    int ldc, int col_off) {
  const int wid = (blockIdx.x * 256 + threadIdx.x) >> 6;
  const int lane = threadIdx.x & 63;
  if (wid >= Nn) return;
  const int half = lane >> 5;
  const int sub = lane & 31;          // owns dims [sub*8, sub*8+8)
  const int e0 = rowptr[wid], e1 = rowptr[wid + 1];
  const unsigned short* mcol = m + sub * 8;
  float acc[8];
#pragma unroll
  for (int q = 0; q < 8; ++q) acc[q] = 0.f;

  for (int base = e0; base < e1; base += 64) {
    const int idx = base + lane;
    int s_ = 0;
    float w_ = 0.f;   // lanes past e1 contribute weight 0
    if (idx < e1) { s_ = csrs[idx]; w_ = csrn[idx]; }
    const int cn = min(64, e1 - base);
    const int npair = (cn + 1) >> 1;
    int sA = __shfl(s_, half);
    float wA = __shfl(w_, half);
    u16x8 vA = *(const u16x8*)(mcol + (size_t)sA * Hd);
    for (int jj = 1; jj < npair; ++jj) {
      const int j = 2 * jj + half;
      const int sB = __shfl(s_, j);
      const float wB = __shfl(w_, j);
      const u16x8 vB = *(const u16x8*)(mcol + (size_t)sB * Hd);
#pragma unroll
      for (int q = 0; q < 8; ++q) acc[q] += wA * bf2f(vA[q]);
      wA = wB; vA = vB;
    }
#pragma unroll
    for (int q = 0; q < 8; ++q) acc[q] += wA * bf2f(vA[q]);
  }

#pragma unroll
  for (int q = 0; q < 8; ++q) acc[q] += __shfl_xor(acc[q], 32);
  if (half == 0) {
    u16x8 o;
#pragma unroll
    for (int q = 0; q < 8; ++q) {
      float v = fmaxf(acc[q] + bias[sub * 8 + q], 0.f);
      o[q] = f2bf(v);
    }
    *(u16x8*)(outp + (size_t)wid * ldc + col_off + sub * 8) = o;
  }
}

// ---------------- cls gather + bias + log_softmax (40 dims) ----------------
__global__ __launch_bounds__(256) void k_gcls(
    const unsigned short* __restrict__ mc, const int* __restrict__ rowptr,
    const int* __restrict__ csrs, const float* __restrict__ csrn,
    const float* __restrict__ clsb, float* __restrict__ outp) {
  const int wid = (blockIdx.x * 256 + threadIdx.x) >> 6;
  const int lane = threadIdx.x & 63;
  if (wid >= Nn) return;
  const int half = lane >> 5;
  const int sub = lane & 31;
  const bool act = sub < 5;
  const int e0 = rowptr[wid], e1 = rowptr[wid + 1];
  float acc[8];
#pragma unroll
  for (int q = 0; q < 8; ++q) acc[q] = 0.f;

  for (int base = e0; base < e1; base += 64) {
    const int idx = base + lane;
    int s_ = 0;
    float w_ = 0.f;
    if (idx < e1) { s_ = csrs[idx]; w_ = csrn[idx]; }
    const int cn = min(64, e1 - base);
    const int npair = (cn + 1) >> 1;
    int sA = __shfl(s_, half);
    float wA = __shfl(w_, half);
    u16x8 vA = act ? *(const u16x8*)(mc + (size_t)sA * Cd + sub * 8) : (u16x8)0;
    for (int jj = 1; jj < npair; ++jj) {
      const int j = 2 * jj + half;
      const int sB = __shfl(s_, j);
      const float wB = __shfl(w_, j);
      const u16x8 vB = act ? *(const u16x8*)(mc + (size_t)sB * Cd + sub * 8) : (u16x8)0;
#pragma unroll
      for (int q = 0; q < 8; ++q) acc[q] += wA * bf2f(vA[q]);
      wA = wB; vA = vB;
    }
#pragma unroll
    for (int q = 0; q < 8; ++q) acc[q] += wA * bf2f(vA[q]);
  }

#pragma unroll
  for (int q = 0; q < 8; ++q) acc[q] += __shfl_xor(acc[q], 32);

  float l[8];
  float mx = -3.4e38f;
  if (act) {
#pragma unroll
    for (int q = 0; q < 8; ++q) {
      l[q] = acc[q] + clsb[sub * 8 + q];
      mx = fmaxf(mx, l[q]);
    }
  }
#pragma unroll
  for (int off = 1; off < 8; off <<= 1) mx = fmaxf(mx, __shfl_xor(mx, off));
  float se = 0.f;
  if (act) {
#pragma unroll
    for (int q = 0; q < 8; ++q) se += expf(l[q] - mx);
  }
#pragma unroll
  for (int off = 1; off < 8; off <<= 1) se += __shfl_xor(se, off);
  const float lse = mx + logf(se);
  if (half == 0 && act) {
    float* o1 = outp + (size_t)wid * Cd + sub * 8;
    float* o2 = o1 + (size_t)Nn * Cd;
#pragma unroll
    for (int q = 0; q < 8; ++q) {
      o1[q] = l[q] - lse;
      o2[q] = l[q];
    }
  }
}

}  // namespace

extern "C" void kernel_launch(void* const* d_in, const int* in_sizes, int n_in,
                              void* d_out, int out_size, void* d_ws, size_t ws_size,
                              hipStream_t stream) {
  (void)in_sizes; (void)n_in; (void)out_size; (void)ws_size;
  const float* x       = (const float*)d_in[0];
  const float* feature = (const float*)d_in[1];
  const int* src       = (const int*)d_in[2];
  const int* dst       = (const int*)d_in[3];
  const float* convW[3] = {(const float*)d_in[4], (const float*)d_in[6], (const float*)d_in[8]};
  const float* convB[3] = {(const float*)d_in[5], (const float*)d_in[7], (const float*)d_in[9]};
  const float* linW[3]  = {(const float*)d_in[10], (const float*)d_in[12], (const float*)d_in[14]};
  const float* linB[3]  = {(const float*)d_in[11], (const float*)d_in[13], (const float*)d_in[15]};
  const float* oweights = (const float*)d_in[16];
  const float* clsW     = (const float*)d_in[17];
  const float* clsB     = (const float*)d_in[18];
  float* out = (float*)d_out;

  char* wsp = (char*)d_ws;
  auto alloc = [&](size_t bytes) -> void* {
    void* p = wsp;
    wsp += (bytes + 255) & ~(size_t)255;
    return p;
  };
  int* cnt      = (int*)alloc((size_t)Nn * 4);
  int* cursor   = (int*)alloc((size_t)Nn * 4);
  int* rowptr   = (int*)alloc((size_t)(Nn + 1) * 4);
  float* dinv   = (float*)alloc((size_t)Nn * 4);
  int* partial  = (int*)alloc((size_t)NB * 4);
  int* poffs    = (int*)alloc((size_t)NB * 4);
  int* csrs     = (int*)alloc((size_t)(Ne + Nn) * 4);
  float* csrn   = (float*)alloc((size_t)(Ne + Nn) * 4);
  unsigned short* WtC0 = (unsigned short*)alloc((size_t)256 * 128 * 2);
  unsigned short* WtC1 = (unsigned short*)alloc((size_t)256 * 512 * 2);
  unsigned short* WtC2 = (unsigned short*)alloc((size_t)256 * 512 * 2);
  unsigned short* WtL0 = (unsigned short*)alloc((size_t)256 * 128 * 2);
  unsigned short* WtL1 = (unsigned short*)alloc((size_t)256 * 256 * 2);
  unsigned short* WtL2 = (unsigned short*)alloc((size_t)256 * 512 * 2);
  unsigned short* WtCl = (unsigned short*)alloc((size_t)64 * 512 * 2);
  unsigned short* mbuf = (unsigned short*)alloc((size_t)Nn * Hd * 2);
  unsigned short* mcls = (unsigned short*)alloc((size_t)Nn * Cd * 2);
  // comb padded +256 rows: direct A-loads of edge blocks read (and discard) pad rows
  unsigned short* comb = (unsigned short*)alloc((size_t)(Nn + 256) * 512 * 2);

  // ---- CSR build (3-level parallel scan)
  k_zero<<<(Nn + 255) / 256, 256, 0, stream>>>(cnt);
  k_count<<<(Ne + 255) / 256, 256, 0, stream>>>(dst, cnt);
  k_partial<<<NB, 256, 0, stream>>>(cnt, partial);
  k_scan_small<<<1, 256, 0, stream>>>(partial, poffs, rowptr);
  k_rowptr<<<NB, 256, 0, stream>>>(cnt, poffs, rowptr, cursor, dinv);
  k_fill<<<(Ne + Nn + 255) / 256, 256, 0, stream>>>(src, dst, dinv, cursor, csrs, csrn);

  // ---- weights: transpose + bf16 + pre-swizzle
  auto wt = [&](const float* W, unsigned short* Wt, int K, int H, int Hpad) {
    k_wt<<<(Hpad * K + 255) / 256, 256, 0, stream>>>(W, Wt, K, H, Hpad);
  };
  wt(convW[0], WtC0, 128, 256, 256);
  wt(convW[1], WtC1, 512, 256, 256);
  wt(convW[2], WtC2, 512, 256, 256);
  wt(linW[0], WtL0, 128, 256, 256);
  wt(linW[1], WtL1, 256, 256, 256);
  wt(linW[2], WtL2, 512, 256, 256);
  wt(clsW, WtCl, 512, 40, 64);

  const int GM = (Nn + 63) / 64;    // 782 blocks, BM=64 BN=256
  const int GC = (Nn + 255) / 256;  // 196 blocks, BM=256 BN=64 (cls)
  const int GB = (Nn * 64) / 256;   // 12500 blocks, one wave per node

  // ---- layer 0
  k_gemm<1, 4><<<GM, 256, 0, stream>>>(x, 0, 128, WtC0, nullptr, nullptr, mbuf, Hd, 0, 256, 0);
  k_gemm<1, 4><<<GM, 256, 0, stream>>>(feature, 0, 128, WtL0, nullptr, linB[0], comb, 512, 0, 256, 1);
  k_gather<<<GB, 256, 0, stream>>>(mbuf, rowptr, csrs, csrn, convB[0], comb, 512, 256);
  // ---- layer 1
  k_gemm<0, 4><<<GM, 256, 0, stream>>>(comb, 512, 512, WtC1, nullptr, nullptr, mbuf, Hd, 0, 256, 0);
  k_gemm<1, 4><<<GM, 256, 0, stream>>>(feature + (size_t)1 * Nn * Fd, 0, 256, WtL1, oweights, linB[1], comb, 512, 0, 256, 1);
  k_gather<<<GB, 256, 0, stream>>>(mbuf, rowptr, csrs, csrn, convB[1], comb, 512, 256);
  // ---- layer 2
  k_gemm<0, 4><<<GM, 256, 0, stream>>>(comb, 512, 512, WtC2, nullptr, nullptr, mbuf, Hd, 0, 256, 0);
  k_gemm<1, 4><<<GM, 256, 0, stream>>>(feature + (size_t)3 * Nn * Fd, 0, 512, WtL2, oweights, linB[2], comb, 512, 0, 256, 1);
  k_gather<<<GB, 256, 0, stream>>>(mbuf, rowptr, csrs, csrn, convB[2], comb, 512, 256);
  // ---- classifier
  k_gemm<0, 1><<<GC, 256, 0, stream>>>(comb, 512, 512, WtCl, nullptr, nullptr, mcls, Cd, 0, 40, 0);
  k_gcls<<<GB, 256, 0, stream>>>(mcls, rowptr, csrs, csrn, clsB, out);
}

// Round 6
// 537.591 us; speedup vs baseline: 1.3260x; 1.1526x over previous
//
#include <hip/hip_runtime.h>

#define DEVI __device__ __forceinline__

namespace {

constexpr int Nn = 50000;   // nodes
constexpr int Ne = 800000;  // edges
constexpr int Fd = 128;     // feature dim
constexpr int Hd = 256;     // hidden
constexpr int Cd = 40;      // classes
constexpr int NB = (Nn + 255) / 256;  // 196 scan blocks

typedef __attribute__((ext_vector_type(8))) short s16x8;   // 8 bf16 MFMA frag
typedef __attribute__((ext_vector_type(8))) unsigned short u16x8;
typedef __attribute__((ext_vector_type(4))) float f32x4;

DEVI unsigned short f2bf(float f) {
  unsigned int u = __builtin_bit_cast(unsigned int, f);
  u += 0x7fffu + ((u >> 16) & 1u);   // RNE
  return (unsigned short)(u >> 16);
}
DEVI float bf2f(unsigned short s) {
  return __builtin_bit_cast(float, ((unsigned int)s) << 16);
}

// Direct HBM->LDS 16B/lane load: M0 = wave-uniform LDS byte base,
// HW writes LDS at M0 + lane*16. gptr is per-lane. (validated R5)
DEVI void gld_lds16(const void* gptr, void* lds_base) {
  const unsigned m0v =
      (unsigned)__builtin_amdgcn_readfirstlane((unsigned)(uintptr_t)lds_base);
  asm volatile("s_mov_b32 m0, %0\n\t"
               "global_load_lds_dwordx4 %1, off"
               :: "s"(m0v), "v"(gptr) : "memory");
}

// ---------------- fused prep: 7 weight transposes (pre-swizzled) + cnt zero ----
// WtS[c][kt*64 + c16*8 + j] = W[(kt*64 + (c16 ^ (c&7))*8 + j)][c]
DEVI void wt_one(const float* __restrict__ W, unsigned short* __restrict__ Wt,
                 int idx, int K, int H) {
  int c = idx / K, k = idx - c * K;
  int kt = k >> 6, c16 = (k >> 3) & 7, j = k & 7;
  int ksrc = (kt << 6) | ((c16 ^ (c & 7)) << 3) | j;
  float v = (c < H) ? W[(size_t)ksrc * H + c] : 0.0f;
  Wt[idx] = f2bf(v);
}

constexpr int WTO0 = 0;
constexpr int WTO1 = WTO0 + 256 * 128;  // convW0
constexpr int WTO2 = WTO1 + 256 * 512;  // convW1
constexpr int WTO3 = WTO2 + 256 * 512;  // convW2
constexpr int WTO4 = WTO3 + 256 * 128;  // linW0
constexpr int WTO5 = WTO4 + 256 * 256;  // linW1
constexpr int WTO6 = WTO5 + 256 * 512;  // linW2
constexpr int WTO7 = WTO6 + 64 * 512;   // clsW
constexpr int PREPTOT = WTO7 + Nn;

__global__ __launch_bounds__(256) void k_prep(
    const float* W0, const float* W1, const float* W2, const float* W3,
    const float* W4, const float* W5, const float* W6,
    unsigned short* T0, unsigned short* T1, unsigned short* T2, unsigned short* T3,
    unsigned short* T4, unsigned short* T5, unsigned short* T6, int* cnt) {
  int idx = blockIdx.x * 256 + threadIdx.x;
  if (idx >= PREPTOT) return;
  if (idx < WTO1)      wt_one(W0, T0, idx - WTO0, 128, 256);
  else if (idx < WTO2) wt_one(W1, T1, idx - WTO1, 512, 256);
  else if (idx < WTO3) wt_one(W2, T2, idx - WTO2, 512, 256);
  else if (idx < WTO4) wt_one(W3, T3, idx - WTO3, 128, 256);
  else if (idx < WTO5) wt_one(W4, T4, idx - WTO4, 256, 256);
  else if (idx < WTO6) wt_one(W5, T5, idx - WTO5, 512, 256);
  else if (idx < WTO7) wt_one(W6, T6, idx - WTO6, 512, 40);
  else cnt[idx - WTO7] = 0;
}

// ---------------- CSR build ----------------
__global__ void k_count(const int* __restrict__ dst, int* __restrict__ cnt) {
  int e = blockIdx.x * 256 + threadIdx.x;
  if (e < Ne) atomicAdd(&cnt[dst[e]], 1);
}

__global__ __launch_bounds__(256) void k_partial(const int* __restrict__ cnt,
                                                 int* __restrict__ partial) {
  __shared__ int red[256];
  const int t = threadIdx.x;
  const int i = blockIdx.x * 256 + t;
  red[t] = (i < Nn) ? cnt[i] + 1 : 0;
  __syncthreads();
#pragma unroll
  for (int off = 128; off; off >>= 1) {
    if (t < off) red[t] += red[t + off];
    __syncthreads();
  }
  if (t == 0) partial[blockIdx.x] = red[0];
}

__global__ __launch_bounds__(256) void k_scan_small(const int* __restrict__ partial,
                                                    int* __restrict__ poffs,
                                                    int* __restrict__ rowptr) {
  __shared__ int s[256];
  const int t = threadIdx.x;
  const int v = (t < NB) ? partial[t] : 0;
  s[t] = v;
  __syncthreads();
#pragma unroll
  for (int off = 1; off < 256; off <<= 1) {
    int add = (t >= off) ? s[t - off] : 0;
    __syncthreads();
    s[t] += add;
    __syncthreads();
  }
  if (t < NB) poffs[t] = s[t] - v;        // exclusive
  if (t == NB - 1) rowptr[Nn] = s[t];     // total = Ne + Nn
}

__global__ __launch_bounds__(256) void k_rowptr(const int* __restrict__ cnt,
                                                const int* __restrict__ poffs,
                                                int* __restrict__ rowptr,
                                                int* __restrict__ cursor,
                                                float* __restrict__ dinv) {
  __shared__ int s[256];
  const int t = threadIdx.x;
  const int i = blockIdx.x * 256 + t;
  const int c = (i < Nn) ? cnt[i] + 1 : 0;
  s[t] = c;
  __syncthreads();
#pragma unroll
  for (int off = 1; off < 256; off <<= 1) {
    int add = (t >= off) ? s[t - off] : 0;
    __syncthreads();
    s[t] += add;
    __syncthreads();
  }
  if (i < Nn) {
    const int excl = s[t] - c + poffs[blockIdx.x];
    rowptr[i] = excl;
    cursor[i] = excl;
    dinv[i] = rsqrtf((float)c);
  }
}

__global__ void k_fill(const int* __restrict__ src, const int* __restrict__ dst,
                       const float* __restrict__ dinv, int* __restrict__ cursor,
                       int* __restrict__ csrs, float* __restrict__ csrn) {
  int e = blockIdx.x * 256 + threadIdx.x;
  if (e < Ne) {
    int s = src[e], d = dst[e];
    int pos = atomicAdd(&cursor[d], 1);
    csrs[pos] = s;
    csrn[pos] = dinv[s] * dinv[d];
  } else if (e < Ne + Nn) {
    int d = e - Ne;  // self loop
    int pos = atomicAdd(&cursor[d], 1);
    csrs[pos] = d;
    float v = dinv[d];
    csrn[pos] = v * v;
  }
}

// ---------------- fused MODE1 GEMM (4 roles), 2-phase pipeline ----------------
// A(r,k) = feat[(k>>7)*Nn*Fd + r*Fd + (k&127)] * (ow ? ow[(k>>7)&1] : 1), f32 src.
// BM=64, BN=256, 4 waves (wc=wid), role = blockIdx.y.
struct GRole {
  const float* A;
  const unsigned short* Wt;
  const float* ow;
  const float* bias;
  unsigned short* C;
  int K;
  int ldc;
  int relu;
};

__global__ __launch_bounds__(256) void k_gemm4(GRole R0, GRole R1, GRole R2, GRole R3) {
  const GRole R = (blockIdx.y == 0) ? R0 : (blockIdx.y == 1) ? R1
                  : (blockIdx.y == 2) ? R2 : R3;
  __shared__ short lA[2][64 * 64];
  __shared__ short lB[2][256 * 64];
  const int tid = threadIdx.x;
  const int lane = tid & 63;
  const int wid = tid >> 6;
  const int wc = wid;                 // wr = 0
  const int row0 = blockIdx.x * 64;
  const size_t NnF = (size_t)Nn * Fd;

  f32x4 acc[4][4];
#pragma unroll
  for (int i = 0; i < 4; ++i)
#pragma unroll
    for (int j = 0; j < 4; ++j) acc[i][j] = (f32x4)0.0f;

  auto issueA = [&](int kt, f32x4 (&A4)[2][2]) {
    const int k0 = kt * 64;
    const int c = k0 >> 7;
    const int f0 = k0 & 127;
#pragma unroll
    for (int i = 0; i < 2; ++i) {
      const int v = tid * 2 + i;
      const int row = v >> 3, c16 = v & 7;
      const int grow = row0 + row;
      const bool rv = grow < Nn;
      const float* p = R.A + (size_t)c * NnF + (size_t)grow * Fd + f0 + c16 * 8;
      A4[i][0] = rv ? *(const f32x4*)p : (f32x4)0.0f;
      A4[i][1] = rv ? *(const f32x4*)(p + 4) : (f32x4)0.0f;
    }
  };
  auto writeA = [&](int kt, f32x4 (&A4)[2][2], short* lAb) {
    const float scale = R.ow ? R.ow[(kt >> 1) & 1] : 1.0f;
#pragma unroll
    for (int i = 0; i < 2; ++i) {
      const int v = tid * 2 + i;
      const int row = v >> 3, c16 = v & 7;
      s16x8 val;
#pragma unroll
      for (int q = 0; q < 4; ++q) val[q] = (short)f2bf(A4[i][0][q] * scale);
#pragma unroll
      for (int q = 0; q < 4; ++q) val[4 + q] = (short)f2bf(A4[i][1][q] * scale);
      int byte = row * 128 + c16 * 16;
      byte ^= (row & 7) << 4;
      *(s16x8*)((char*)lAb + byte) = val;
    }
  };
  auto issueB = [&](int kt, short* lBb) {
    const int k0 = kt * 64;
#pragma unroll
    for (int i = 0; i < 8; ++i) {
      const int iss = wid * 8 + i;
      const int col = iss * 8 + (lane >> 3);
      gld_lds16(R.Wt + (size_t)col * R.K + k0 + (lane & 7) * 8, lBb + iss * 512);
    }
  };
  auto compute = [&](const short* lAb, const short* lBb) {
#pragma unroll
    for (int kk = 0; kk < 2; ++kk) {
      s16x8 af[4], bv[4];
#pragma unroll
      for (int mi = 0; mi < 4; ++mi) {
        int r = mi * 16 + (lane & 15);
        int byte = r * 128 + kk * 64 + (lane >> 4) * 16;
        byte ^= (r & 7) << 4;
        af[mi] = *(const s16x8*)((const char*)lAb + byte);
      }
#pragma unroll
      for (int ni = 0; ni < 4; ++ni) {
        int c = wc * 64 + ni * 16 + (lane & 15);
        int byte = c * 128 + kk * 64 + (lane >> 4) * 16;
        byte ^= (c & 7) << 4;
        bv[ni] = *(const s16x8*)((const char*)lBb + byte);
      }
#pragma unroll
      for (int mi = 0; mi < 4; ++mi)
#pragma unroll
        for (int ni = 0; ni < 4; ++ni)
          acc[mi][ni] = __builtin_amdgcn_mfma_f32_16x16x32_bf16(af[mi], bv[ni], acc[mi][ni], 0, 0, 0);
    }
  };

  const int nkt = R.K >> 6;
  f32x4 Areg[2][2];
  issueA(0, Areg);
  issueB(0, lB[0]);
  asm volatile("s_waitcnt vmcnt(0)" ::: "memory");
  writeA(0, Areg, lA[0]);
  __syncthreads();
  int cur = 0;
  for (int kt = 0; kt < nkt - 1; ++kt) {
    f32x4 Anext[2][2];
    issueA(kt + 1, Anext);
    issueB(kt + 1, lB[cur ^ 1]);
    compute(lA[cur], lB[cur]);
    asm volatile("s_waitcnt vmcnt(0)" ::: "memory");
    writeA(kt + 1, Anext, lA[cur ^ 1]);
    __syncthreads();
    cur ^= 1;
  }
  compute(lA[cur], lB[cur]);

  // epilogue
#pragma unroll
  for (int ni = 0; ni < 4; ++ni) {
    const int col = wc * 64 + ni * 16 + (lane & 15);
    const float bvl = R.bias ? R.bias[col] : 0.0f;
#pragma unroll
    for (int mi = 0; mi < 4; ++mi) {
      const int rb = row0 + mi * 16 + ((lane >> 4) << 2);
#pragma unroll
      for (int q = 0; q < 4; ++q) {
        int r = rb + q;
        if (r < Nn) {
          float vv = acc[mi][ni][q] + bvl;
          if (R.relu) vv = fmaxf(vv, 0.0f);
          R.C[(size_t)r * R.ldc + col] = f2bf(vv);
        }
      }
    }
  }
}

// ---------------- MODE0 GEMM (bf16 A, direct-load both tiles), 2-phase --------
// A must be row-padded past grid (comb has +256 pad rows). No bias/relu.
template <int NWC>
__global__ __launch_bounds__(256) void k_gemmB(
    const unsigned short* __restrict__ A, int lda, int K,
    const unsigned short* __restrict__ Wt, unsigned short* __restrict__ C,
    int ldc, int ncols) {
  constexpr int WRN = 4 / NWC;
  constexpr int BM = WRN * 64;
  constexpr int BN = NWC * 64;
  constexpr int AISSW = BM / 32;
  constexpr int BISSW = BN / 32;
  __shared__ short lA[2][BM * 64];
  __shared__ short lB[2][BN * 64];
  const int tid = threadIdx.x;
  const int lane = tid & 63;
  const int wid = tid >> 6;
  const int wr = wid / NWC;
  const int wc = wid % NWC;
  const int row0 = blockIdx.x * BM;
  const int c16a = (lane & 7) ^ ((lane >> 3) & 7);

  f32x4 acc[4][4];
#pragma unroll
  for (int i = 0; i < 4; ++i)
#pragma unroll
    for (int j = 0; j < 4; ++j) acc[i][j] = (f32x4)0.0f;

  auto stage = [&](int kt, short* lAb, short* lBb) {
    const int k0 = kt * 64;
#pragma unroll
    for (int i = 0; i < AISSW; ++i) {
      const int iss = wid * AISSW + i;
      const int row = row0 + iss * 8 + (lane >> 3);
      gld_lds16(A + (size_t)row * lda + k0 + c16a * 8, lAb + iss * 512);
    }
#pragma unroll
    for (int i = 0; i < BISSW; ++i) {
      const int iss = wid * BISSW + i;
      const int col = iss * 8 + (lane >> 3);
      gld_lds16(Wt + (size_t)col * K + k0 + (lane & 7) * 8, lBb + iss * 512);
    }
  };
  auto compute = [&](const short* lAb, const short* lBb) {
#pragma unroll
    for (int kk = 0; kk < 2; ++kk) {
      s16x8 af[4], bv[4];
#pragma unroll
      for (int mi = 0; mi < 4; ++mi) {
        int r = wr * 64 + mi * 16 + (lane & 15);
        int byte = r * 128 + kk * 64 + (lane >> 4) * 16;
        byte ^= (r & 7) << 4;
        af[mi] = *(const s16x8*)((const char*)lAb + byte);
      }
#pragma unroll
      for (int ni = 0; ni < 4; ++ni) {
        int c = wc * 64 + ni * 16 + (lane & 15);
        int byte = c * 128 + kk * 64 + (lane >> 4) * 16;
        byte ^= (c & 7) << 4;
        bv[ni] = *(const s16x8*)((const char*)lBb + byte);
      }
#pragma unroll
      for (int mi = 0; mi < 4; ++mi)
#pragma unroll
        for (int ni = 0; ni < 4; ++ni)
          acc[mi][ni] = __builtin_amdgcn_mfma_f32_16x16x32_bf16(af[mi], bv[ni], acc[mi][ni], 0, 0, 0);
    }
  };

  const int nkt = K >> 6;
  stage(0, lA[0], lB[0]);
  asm volatile("s_waitcnt vmcnt(0)" ::: "memory");
  __syncthreads();
  int cur = 0;
  for (int kt = 0; kt < nkt - 1; ++kt) {
    stage(kt + 1, lA[cur ^ 1], lB[cur ^ 1]);
    compute(lA[cur], lB[cur]);
    asm volatile("s_waitcnt vmcnt(0)" ::: "memory");
    __syncthreads();
    cur ^= 1;
  }
  compute(lA[cur], lB[cur]);

#pragma unroll
  for (int ni = 0; ni < 4; ++ni) {
    const int col = wc * 64 + ni * 16 + (lane & 15);
    if (col >= ncols) continue;
#pragma unroll
    for (int mi = 0; mi < 4; ++mi) {
      const int rb = row0 + wr * 64 + mi * 16 + ((lane >> 4) << 2);
#pragma unroll
      for (int q = 0; q < 4; ++q) {
        int r = rb + q;
        if (r < Nn) C[(size_t)r * ldc + col] = f2bf(acc[mi][ni][q]);
      }
    }
  }
}

// ---------------- gather 256-dim: one wave per node, depth-4 pipeline ---------
__global__ __launch_bounds__(256) void k_gather(
    const unsigned short* __restrict__ m, const int* __restrict__ rowptr,
    const int* __restrict__ csrs, const float* __restrict__ csrn,
    const float* __restrict__ bias, unsigned short* __restrict__ outp,
    int ldc, int col_off) {
  const int wid = (blockIdx.x * 256 + threadIdx.x) >> 6;
  const int lane = threadIdx.x & 63;
  if (wid >= Nn) return;
  const int half = lane >> 5;
  const int sub = lane & 31;          // owns dims [sub*8, sub*8+8)
  const int e0 = rowptr[wid], e1 = rowptr[wid + 1];
  const unsigned short* mcol = m + sub * 8;
  float acc[8];
#pragma unroll
  for (int q = 0; q < 8; ++q) acc[q] = 0.f;

  for (int base = e0; base < e1; base += 64) {
    const int idx = base + lane;
    int s_ = 0;
    float w_ = 0.f;
    if (idx < e1) { s_ = csrs[idx]; w_ = csrn[idx]; }
    const int cn = min(64, e1 - base);
    const int npair = (cn + 1) >> 1;
    float w0, w1, w2, w3;
    u16x8 v0, v1, v2, v3;
    auto pick = [&](int p, float& w, u16x8& v) {
      if (p < npair) {           // wave-uniform branch
        const int j = 2 * p + half;
        const int ss = __shfl(s_, j);
        w = __shfl(w_, j);
        v = *(const u16x8*)(mcol + (size_t)ss * Hd);
      } else { w = 0.f; v = (u16x8)0; }
    };
    pick(0, w0, v0); pick(1, w1, v1); pick(2, w2, v2); pick(3, w3, v3);
    for (int p0 = 0; p0 < npair; p0 += 4) {
#pragma unroll
      for (int q = 0; q < 8; ++q) acc[q] += w0 * bf2f(v0[q]);
      pick(p0 + 4, w0, v0);
#pragma unroll
      for (int q = 0; q < 8; ++q) acc[q] += w1 * bf2f(v1[q]);
      pick(p0 + 5, w1, v1);
#pragma unroll
      for (int q = 0; q < 8; ++q) acc[q] += w2 * bf2f(v2[q]);
      pick(p0 + 6, w2, v2);
#pragma unroll
      for (int q = 0; q < 8; ++q) acc[q] += w3 * bf2f(v3[q]);
      pick(p0 + 7, w3, v3);
    }
  }

#pragma unroll
  for (int q = 0; q < 8; ++q) acc[q] += __shfl_xor(acc[q], 32);
  if (half == 0) {
    u16x8 o;
#pragma unroll
    for (int q = 0; q < 8; ++q) {
      float v = fmaxf(acc[q] + bias[sub * 8 + q], 0.f);
      o[q] = f2bf(v);
    }
    *(u16x8*)(outp + (size_t)wid * ldc + col_off + sub * 8) = o;
  }
}

// ---------------- cls gather + bias + log_softmax (40 dims) ----------------
__global__ __launch_bounds__(256) void k_gcls(
    const unsigned short* __restrict__ mc, const int* __restrict__ rowptr,
    const int* __restrict__ csrs, const float* __restrict__ csrn,
    const float* __restrict__ clsb, float* __restrict__ outp) {
  const int wid = (blockIdx.x * 256 + threadIdx.x) >> 6;
  const int lane = threadIdx.x & 63;
  if (wid >= Nn) return;
  const int half = lane >> 5;
  const int sub = lane & 31;
  const bool act = sub < 5;
  const int e0 = rowptr[wid], e1 = rowptr[wid + 1];
  float acc[8];
#pragma unroll
  for (int q = 0; q < 8; ++q) acc[q] = 0.f;

  for (int base = e0; base < e1; base += 64) {
    const int idx = base + lane;
    int s_ = 0;
    float w_ = 0.f;
    if (idx < e1) { s_ = csrs[idx]; w_ = csrn[idx]; }
    const int cn = min(64, e1 - base);
    const int npair = (cn + 1) >> 1;
    int sA = __shfl(s_, half);
    float wA = __shfl(w_, half);
    u16x8 vA = act ? *(const u16x8*)(mc + (size_t)sA * Cd + sub * 8) : (u16x8)0;
    for (int jj = 1; jj < npair; ++jj) {
      const int j = 2 * jj + half;
      const int sB = __shfl(s_, j);
      const float wB = __shfl(w_, j);
      const u16x8 vB = act ? *(const u16x8*)(mc + (size_t)sB * Cd + sub * 8) : (u16x8)0;
#pragma unroll
      for (int q = 0; q < 8; ++q) acc[q] += wA * bf2f(vA[q]);
      wA = wB; vA = vB;
    }
#pragma unroll
    for (int q = 0; q < 8; ++q) acc[q] += wA * bf2f(vA[q]);
  }

#pragma unroll
  for (int q = 0; q < 8; ++q) acc[q] += __shfl_xor(acc[q], 32);

  float l[8];
  float mx = -3.4e38f;
  if (act) {
#pragma unroll
    for (int q = 0; q < 8; ++q) {
      l[q] = acc[q] + clsb[sub * 8 + q];
      mx = fmaxf(mx, l[q]);
    }
  }
#pragma unroll
  for (int off = 1; off < 8; off <<= 1) mx = fmaxf(mx, __shfl_xor(mx, off));
  float se = 0.f;
  if (act) {
#pragma unroll
    for (int q = 0; q < 8; ++q) se += expf(l[q] - mx);
  }
#pragma unroll
  for (int off = 1; off < 8; off <<= 1) se += __shfl_xor(se, off);
  const float lse = mx + logf(se);
  if (half == 0 && act) {
    float* o1 = outp + (size_t)wid * Cd + sub * 8;
    float* o2 = o1 + (size_t)Nn * Cd;
#pragma unroll
    for (int q = 0; q < 8; ++q) {
      o1[q] = l[q] - lse;
      o2[q] = l[q];
    }
  }
}

}  // namespace

extern "C" void kernel_launch(void* const* d_in, const int* in_sizes, int n_in,
                              void* d_out, int out_size, void* d_ws, size_t ws_size,
                              hipStream_t stream) {
  (void)in_sizes; (void)n_in; (void)out_size; (void)ws_size;
  const float* x       = (const float*)d_in[0];
  const float* feature = (const float*)d_in[1];
  const int* src       = (const int*)d_in[2];
  const int* dst       = (const int*)d_in[3];
  const float* convW[3] = {(const float*)d_in[4], (const float*)d_in[6], (const float*)d_in[8]};
  const float* convB[3] = {(const float*)d_in[5], (const float*)d_in[7], (const float*)d_in[9]};
  const float* linW[3]  = {(const float*)d_in[10], (const float*)d_in[12], (const float*)d_in[14]};
  const float* linB[3]  = {(const float*)d_in[11], (const float*)d_in[13], (const float*)d_in[15]};
  const float* oweights = (const float*)d_in[16];
  const float* clsW     = (const float*)d_in[17];
  const float* clsB     = (const float*)d_in[18];
  float* out = (float*)d_out;

  char* wsp = (char*)d_ws;
  auto alloc = [&](size_t bytes) -> void* {
    void* p = wsp;
    wsp += (bytes + 255) & ~(size_t)255;
    return p;
  };
  int* cnt      = (int*)alloc((size_t)Nn * 4);
  int* cursor   = (int*)alloc((size_t)Nn * 4);
  int* rowptr   = (int*)alloc((size_t)(Nn + 1) * 4);
  float* dinv   = (float*)alloc((size_t)Nn * 4);
  int* partial  = (int*)alloc((size_t)NB * 4);
  int* poffs    = (int*)alloc((size_t)NB * 4);
  int* csrs     = (int*)alloc((size_t)(Ne + Nn) * 4);
  float* csrn   = (float*)alloc((size_t)(Ne + Nn) * 4);
  unsigned short* WtC0 = (unsigned short*)alloc((size_t)256 * 128 * 2);
  unsigned short* WtC1 = (unsigned short*)alloc((size_t)256 * 512 * 2);
  unsigned short* WtC2 = (unsigned short*)alloc((size_t)256 * 512 * 2);
  unsigned short* WtL0 = (unsigned short*)alloc((size_t)256 * 128 * 2);
  unsigned short* WtL1 = (unsigned short*)alloc((size_t)256 * 256 * 2);
  unsigned short* WtL2 = (unsigned short*)alloc((size_t)256 * 512 * 2);
  unsigned short* WtCl = (unsigned short*)alloc((size_t)64 * 512 * 2);
  unsigned short* mbuf = (unsigned short*)alloc((size_t)Nn * Hd * 2);
  unsigned short* mcls = (unsigned short*)alloc((size_t)Nn * Cd * 2);
  // combs padded +256 rows: direct A-loads of edge blocks read (and discard) pad
  unsigned short* comb0 = (unsigned short*)alloc((size_t)(Nn + 256) * 512 * 2);
  unsigned short* comb1 = (unsigned short*)alloc((size_t)(Nn + 256) * 512 * 2);
  unsigned short* comb2 = (unsigned short*)alloc((size_t)(Nn + 256) * 512 * 2);

  // ---- prep (weights + zero) and CSR build
  k_prep<<<(PREPTOT + 255) / 256, 256, 0, stream>>>(
      convW[0], convW[1], convW[2], linW[0], linW[1], linW[2], clsW,
      WtC0, WtC1, WtC2, WtL0, WtL1, WtL2, WtCl, cnt);
  k_count<<<(Ne + 255) / 256, 256, 0, stream>>>(dst, cnt);
  k_partial<<<NB, 256, 0, stream>>>(cnt, partial);
  k_scan_small<<<1, 256, 0, stream>>>(partial, poffs, rowptr);
  k_rowptr<<<NB, 256, 0, stream>>>(cnt, poffs, rowptr, cursor, dinv);
  k_fill<<<(Ne + Nn + 255) / 256, 256, 0, stream>>>(src, dst, dinv, cursor, csrs, csrn);

  const int GM = (Nn + 63) / 64;    // 782
  const int GC = (Nn + 255) / 256;  // 196
  const int GB = (Nn * 64) / 256;   // 12500, one wave per node

  // ---- all input-only GEMMs in ONE launch (conv0 + lin0 + lin1 + lin2)
  GRole rConv0{x,                              WtC0, nullptr,  nullptr, mbuf,  128, Hd,  0};
  GRole rLin0 {feature,                        WtL0, nullptr,  linB[0], comb0, 128, 512, 1};
  GRole rLin1 {feature + (size_t)1 * Nn * Fd,  WtL1, oweights, linB[1], comb1, 256, 512, 1};
  GRole rLin2 {feature + (size_t)3 * Nn * Fd,  WtL2, oweights, linB[2], comb2, 512, 512, 1};
  k_gemm4<<<dim3(GM, 4), 256, 0, stream>>>(rConv0, rLin0, rLin1, rLin2);

  // ---- layer chain: gather(i) -> conv(i+1)
  k_gather<<<GB, 256, 0, stream>>>(mbuf, rowptr, csrs, csrn, convB[0], comb0, 512, 256);
  k_gemmB<4><<<GM, 256, 0, stream>>>(comb0, 512, 512, WtC1, mbuf, Hd, 256);
  k_gather<<<GB, 256, 0, stream>>>(mbuf, rowptr, csrs, csrn, convB[1], comb1, 512, 256);
  k_gemmB<4><<<GM, 256, 0, stream>>>(comb1, 512, 512, WtC2, mbuf, Hd, 256);
  k_gather<<<GB, 256, 0, stream>>>(mbuf, rowptr, csrs, csrn, convB[2], comb2, 512, 256);
  // ---- classifier
  k_gemmB<1><<<GC, 256, 0, stream>>>(comb2, 512, 512, WtCl, mcls, Cd, 40);
  k_gcls<<<GB, 256, 0, stream>>>(mcls, rowptr, csrs, csrn, clsB, out);
}